// Round 7
// baseline (852.401 us; speedup 1.0000x reference)
//
#include <hip/hip_runtime.h>
#include <hip/hip_fp16.h>
#include <math.h>

#define BB 512   // batch
#define TT 1024  // max seq len
#define HH 128   // hidden

// ---------------------------------------------------------------------------
// Kernel 1: bitonic sort of (length, idx) composite keys, descending.
// Load-balance only; any permutation is still correct.
// ---------------------------------------------------------------------------
__global__ __launch_bounds__(512) void sort_kernel(const int* __restrict__ lengths,
                                                   int* __restrict__ order) {
  __shared__ int comp[BB];
  const int t = threadIdx.x;
  comp[t] = (lengths[t] << 9) | t;  // unique composite keys
  __syncthreads();
  for (int k = 2; k <= BB; k <<= 1) {
    for (int j = k >> 1; j > 0; j >>= 1) {
      int ixj = t ^ j;
      if (ixj > t) {
        int a = comp[t], b = comp[ixj];
        bool descBlock = ((t & k) == 0);
        bool doSwap = descBlock ? (a < b) : (a > b);
        if (doSwap) { comp[t] = b; comp[ixj] = a; }
      }
      __syncthreads();
    }
  }
  order[t] = comp[t] & 511;
}

// ---------------------------------------------------------------------------
// Kernel 2: GRU recurrence. 256 blocks x 1024 threads (16 waves), 1 block/CU.
// Thread (i = tid&127, kc = tid>>7): 16-wide K-chunk, weights held as
// 24 PACKED fp16 VGPRs consumed directly by v_fma_mix_f32 (fp32 accumulate).
//
// ROUND HISTORY: r1-r6 proved the RA spills any >~50 live VGPRs regardless
// of asm pins / waves_per_eu, so fp32-resident weights (48-96 regs) always
// degraded to a ~192KB/CU-step L2 stream (~1700 cyc/step, the measured
// plateau). fp16 packing fits the resident set (~50 regs) under the
// allocator's demonstrated budget; worst case (still spilled) it halves the
// stream bytes.
// ---------------------------------------------------------------------------
__global__ __launch_bounds__(1024)
__attribute__((amdgpu_waves_per_eu(4, 4)))
void gru_main(
    const float* __restrict__ x, const int* __restrict__ lengths,
    const float* __restrict__ w_ih, const float* __restrict__ w_hh,
    const float* __restrict__ b_ih, const float* __restrict__ b_hh,
    const float* __restrict__ head_w, const float* __restrict__ head_b,
    const int* __restrict__ order, float* __restrict__ out) {
  __shared__ __align__(16) float hs[HH];        // current hidden state (fp32)
  __shared__ float parts[3][8][HH];             // split-K partials (12 KB)
  __shared__ __align__(16) float xrow[TT * 2];  // staged x row (8 KB)

  const int tid = threadIdx.x;
  const int i  = tid & (HH - 1);  // output row within a gate
  const int kc = tid >> 7;        // k-chunk 0..7 (16 floats), wave-uniform

  // --- one-time: weights -> fp16 RTN, packed 2/VGPR (24 regs), pinned ---
  unsigned int wp[3][8];  // wp[g][q] holds halves j=2q,2q+1 of
                          // w_hh[g*128+i][kc*16 + j]
#pragma unroll
  for (int g = 0; g < 3; ++g)
#pragma unroll
    for (int q = 0; q < 8; ++q) {
      const float w0 = w_hh[(g * HH + i) * HH + kc * 16 + 2 * q + 0];
      const float w1 = w_hh[(g * HH + i) * HH + kc * 16 + 2 * q + 1];
      __half2 h2;
      h2.x = __float2half(w0);  // RTN
      h2.y = __float2half(w1);
      wp[g][q] = *reinterpret_cast<unsigned int*>(&h2);
      asm volatile("" : "+v"(wp[g][q]));  // opaque def
    }

  // --- phase-2 constants ---
  float wi0[3], wi1[3], bi[3], bh[3];
#pragma unroll
  for (int g = 0; g < 3; ++g) {
    wi0[g] = w_ih[(g * HH + i) * 2 + 0];
    wi1[g] = w_ih[(g * HH + i) * 2 + 1];
    bi[g]  = b_ih[g * HH + i];
    bh[g]  = b_hh[g * HH + i];
  }
  const float hw = head_w[i];
  const float hb = head_b[0];

  for (int pb = 0; pb < 2; ++pb) {
    const int slot = pb ? (BB - 1 - (int)blockIdx.x) : (int)blockIdx.x;
    const int b = order[slot];
    const int len = lengths[b];  // in [1, 1024]

    // stage this batch's x row (coalesced) + init h
    for (int ofs = tid; ofs < len * 2; ofs += 1024)
      xrow[ofs] = x[(size_t)b * (TT * 2) + ofs];
    if (tid < HH) hs[tid] = 0.0f;
    __syncthreads();

    for (int t = 0; t < len; ++t) {
      // ---- phase 1: split-K matvec, fp16-packed weights via v_fma_mix ----
      float pr = 0.f, pz = 0.f, pn = 0.f;
#pragma unroll
      for (int qq = 0; qq < 4; ++qq) {
        // broadcast read of 4 h floats (wave-uniform address -> free)
        const float4 h4 =
            *reinterpret_cast<const float4*>(&hs[kc * 16 + qq * 4]);
        const float h0 = h4.x, h1 = h4.y, h2f = h4.z, h3 = h4.w;
        const unsigned int a0 = wp[0][2 * qq], a1 = wp[0][2 * qq + 1];
        const unsigned int b0 = wp[1][2 * qq], b1 = wp[1][2 * qq + 1];
        const unsigned int c0 = wp[2][2 * qq], c1 = wp[2][2 * qq + 1];
        asm volatile(
            "v_fma_mix_f32 %0, %3, %6, %0 op_sel:[0,0,0] op_sel_hi:[1,0,0]\n\t"
            "v_fma_mix_f32 %1, %4, %6, %1 op_sel:[0,0,0] op_sel_hi:[1,0,0]\n\t"
            "v_fma_mix_f32 %2, %5, %6, %2 op_sel:[0,0,0] op_sel_hi:[1,0,0]\n\t"
            "v_fma_mix_f32 %0, %3, %7, %0 op_sel:[1,0,0] op_sel_hi:[1,0,0]\n\t"
            "v_fma_mix_f32 %1, %4, %7, %1 op_sel:[1,0,0] op_sel_hi:[1,0,0]\n\t"
            "v_fma_mix_f32 %2, %5, %7, %2 op_sel:[1,0,0] op_sel_hi:[1,0,0]\n\t"
            "v_fma_mix_f32 %0, %8, %10, %0 op_sel:[0,0,0] op_sel_hi:[1,0,0]\n\t"
            "v_fma_mix_f32 %1, %9, %10, %1 op_sel:[0,0,0] op_sel_hi:[1,0,0]\n\t"
            "v_fma_mix_f32 %2, %11, %10, %2 op_sel:[0,0,0] op_sel_hi:[1,0,0]\n\t"
            "v_fma_mix_f32 %0, %8, %12, %0 op_sel:[1,0,0] op_sel_hi:[1,0,0]\n\t"
            "v_fma_mix_f32 %1, %9, %12, %1 op_sel:[1,0,0] op_sel_hi:[1,0,0]\n\t"
            "v_fma_mix_f32 %2, %11, %12, %2 op_sel:[1,0,0] op_sel_hi:[1,0,0]"
            : "+v"(pr), "+v"(pz), "+v"(pn)
            : "v"(a0), "v"(b0), "v"(c0), "v"(h0), "v"(h1),
              "v"(a1), "v"(b1), "v"(h2f), "v"(c1), "v"(h3));
      }
      parts[0][kc][i] = pr;
      parts[1][kc][i] = pz;
      parts[2][kc][i] = pn;
      __syncthreads();

      // ---- phase 2: reduce 8 partials/gate + gates + h update (tid<128) ----
      if (tid < HH) {
        float gr = bh[0], gz = bh[1], gn = bh[2];
#pragma unroll
        for (int c = 0; c < 8; ++c) gr += parts[0][c][tid];
#pragma unroll
        for (int c = 0; c < 8; ++c) gz += parts[1][c][tid];
#pragma unroll
        for (int c = 0; c < 8; ++c) gn += parts[2][c][tid];
        const float x0 = xrow[t * 2 + 0];
        const float x1 = xrow[t * 2 + 1];
        const float ar = bi[0] + x0 * wi0[0] + x1 * wi1[0] + gr;
        const float az = bi[1] + x0 * wi0[1] + x1 * wi1[1] + gz;
        const float an = bi[2] + x0 * wi0[2] + x1 * wi1[2];
        const float r = 1.0f / (1.0f + __expf(-ar));
        const float z = 1.0f / (1.0f + __expf(-az));
        const float a = an + r * gn;          // tanh argument
        const float e2 = __expf(-2.0f * a);
        const float n = (1.0f - e2) / (1.0f + e2);
        hs[tid] = (1.0f - z) * n + z * hs[tid];
      }
      __syncthreads();
    }

    // ---- head: out[b] = dot(h, head_w) + head_b ----
    if (tid < HH) parts[0][0][tid] = hs[tid] * hw;
    __syncthreads();
    if (tid == 0) {
      float s = hb;
      for (int q = 0; q < HH; ++q) s += parts[0][0][q];
      out[b] = s;
    }
    __syncthreads();  // protect hs/parts before next batch reuses them
  }
}

extern "C" void kernel_launch(void* const* d_in, const int* in_sizes, int n_in,
                              void* d_out, int out_size, void* d_ws, size_t ws_size,
                              hipStream_t stream) {
  const float* x       = (const float*)d_in[0];
  const int*   lengths = (const int*)d_in[1];
  const float* w_ih    = (const float*)d_in[2];
  const float* w_hh    = (const float*)d_in[3];
  const float* b_ih    = (const float*)d_in[4];
  const float* b_hh    = (const float*)d_in[5];
  const float* head_w  = (const float*)d_in[6];
  const float* head_b  = (const float*)d_in[7];
  float* out = (float*)d_out;
  int* order = (int*)d_ws;  // 512 ints of scratch

  sort_kernel<<<1, 512, 0, stream>>>(lengths, order);
  gru_main<<<256, 1024, 0, stream>>>(x, lengths, w_ih, w_hh, b_ih, b_hh,
                                     head_w, head_b, order, out);
}